// Round 1
// baseline (105.823 us; speedup 1.0000x reference)
//
#include <hip/hip_runtime.h>

typedef __attribute__((ext_vector_type(8))) short bf16x8;
typedef __attribute__((ext_vector_type(4))) float f32x4;
typedef __attribute__((ext_vector_type(4))) int i32x4;
typedef __attribute__((ext_vector_type(4))) float float4v;

#define MFMA16(a, b, c) __builtin_amdgcn_mfma_f32_16x16x32_bf16((a), (b), (c), 0, 0, 0)

__device__ __forceinline__ unsigned short f2bf(float f) {
    unsigned u = __builtin_bit_cast(unsigned, f);
    u += 0x7fffu + ((u >> 16) & 1u);
    return (unsigned short)(u >> 16);
}
__device__ __forceinline__ float bf2f(unsigned short s) {
    unsigned u = ((unsigned)s) << 16;
    return __builtin_bit_cast(float, u);
}
__device__ __forceinline__ int pkbf(float a, float b) {
    return (int)f2bf(a) | ((int)f2bf(b) << 16);
}

// LDS map (bytes), total 159744 (< 163840):
//   [0, 131072)       blk^T bf16 [m=512][c=128], byte = (m*256 + 2c) ^ (((m>>2)&7)<<4)
//                     reused at end: O bf16 [c=128][nq=512], byte = c*1024 + 2*(nq ^ ((c&7)<<3))
//   [131072, 147456)  per-wave qhat scratch, then Khat bf16 [mk=512][d=16]: 131072 + mk*32 + 2d
//   [147456, 157696)  V tile bf16 [c=128][mk pad 40]: 147456 + c*80 + 2mk
//   [157696, 159744)  l[512] f32 (softmax denominators)

__global__ __launch_bounds__(512, 2) void battn_kernel(
    const float* __restrict__ x,
    const float* __restrict__ Wq, const float* __restrict__ bq,
    const float* __restrict__ Wk, const float* __restrict__ bk,
    const float* __restrict__ Wv, const float* __restrict__ bv,
    const float* __restrict__ gamma, float* __restrict__ out)
{
    __shared__ __attribute__((aligned(128))) char smem[159744];
    const int bid = blockIdx.x;
    const int tid = threadIdx.x;

    if (bid >= 64) {
        // ---------------- copy path: all non-diagonal float4 chunks ----------------
        const float4v* __restrict__ xin = (const float4v*)x;
        float4v* __restrict__ o4 = (float4v*)out;
        const int total = 1 << 23;  // 33.55M elems / 4
        for (int u = (bid - 64) * 512 + tid; u < total; u += 384 * 512) {
            // elem e = 4u: wblk = (u>>1)&7, dblk = (u>>13)&7 ; copy iff different
            if ((((u >> 1) ^ (u >> 13)) & 7) != 0) {
                o4[u] = xin[u];
            }
        }
        return;
    }

    // ---------------- attention path: one workgroup per diagonal block p ----------------
    const int p = bid;
    const int ib = p >> 3, jb = p & 7;                   // d/w-block, h-block
    const int vbase = ib * 8 * 4096 + jb * 8 * 64 + ib * 8;
    const int lane = tid & 63, wv = tid >> 6;
    const int g = lane >> 4, c15 = lane & 15;

    // phase 0: stage x block -> blk^T bf16 (swizzled). m = dd*64+hh*8+ww.
    for (int it = 0; it < 32; ++it) {
        int ch = it * 512 + tid;            // 16384 float4 chunks
        int c = ch >> 7;
        int m = (ch & 127) * 4;             // 4 consecutive w within one run
        int vox = ((m >> 6) << 12) + (((m >> 3) & 7) << 6) + (m & 7);
        float4v v = *(const float4v*)(x + c * 262144 + vbase + vox);
        char* bp = smem + ((m * 256 + 2 * c) ^ (((m >> 2) & 7) << 4));
        *(unsigned short*)(bp)       = f2bf(v[0]);
        *(unsigned short*)(bp + 256) = f2bf(v[1]);
        *(unsigned short*)(bp + 512) = f2bf(v[2]);
        *(unsigned short*)(bp + 768) = f2bf(v[3]);
    }

    // weight fragments (fp32 global -> bf16 regs); B-frag col = c15, k = 8g+j
    bf16x8 wqf[4], wkf[4], wvf[4];
    #pragma unroll
    for (int ks = 0; ks < 4; ++ks) {
        const float* sq = Wq + c15 * 128 + ks * 32 + g * 8;
        const float* sk = Wk + c15 * 128 + ks * 32 + g * 8;
        const float* sv = Wv + (wv * 16 + c15) * 128 + ks * 32 + g * 8;
        #pragma unroll
        for (int e = 0; e < 8; ++e) {
            wqf[ks][e] = (short)f2bf(sq[e]);
            wkf[ks][e] = (short)f2bf(sk[e]);
            wvf[ks][e] = (short)f2bf(sv[e]);
        }
    }
    const float bqv = bq[c15], bkv = bk[c15];
    const f32x4 zacc = {0.f, 0.f, 0.f, 0.f};
    const bf16x8 zfrag = (bf16x8)(short)0;

    __syncthreads();

    // phase 1: qhat^T[m][d] for this wave's 64 queries -> per-wave scratch -> B-frags in regs
    #pragma unroll
    for (int qi = 0; qi < 4; ++qi) {
        f32x4 acc = zacc;
        int mrow = wv * 64 + qi * 16 + c15;
        int sw = ((mrow >> 2) & 7) << 4;
        #pragma unroll
        for (int ks = 0; ks < 4; ++ks) {
            bf16x8 af = *(const bf16x8*)(smem + ((mrow * 256 + ks * 64 + g * 16) ^ sw));
            acc = MFMA16(af, wqf[ks], acc);
        }
        #pragma unroll
        for (int r = 0; r < 4; ++r) {
            int nql = qi * 16 + g * 4 + r;
            *(unsigned short*)(smem + 131072 + wv * 2048 + nql * 32 + 2 * c15) = f2bf(acc[r] + bqv);
        }
    }
    __syncthreads();
    bf16x8 qf[4];
    #pragma unroll
    for (int t = 0; t < 4; ++t) {
        bf16x8 v = zfrag;
        if (g < 2) v = *(const bf16x8*)(smem + 131072 + wv * 2048 + (t * 16 + c15) * 32 + g * 16);
        qf[t] = v;   // col = nq-in-tile, k = d (zeros for k>=16)
    }
    __syncthreads();

    // phase 2: Khat[mk][d] for all 512 keys (overwrites scratch)
    #pragma unroll
    for (int qi = 0; qi < 4; ++qi) {
        f32x4 acc = zacc;
        int mrow = wv * 64 + qi * 16 + c15;
        int sw = ((mrow >> 2) & 7) << 4;
        #pragma unroll
        for (int ks = 0; ks < 4; ++ks) {
            bf16x8 af = *(const bf16x8*)(smem + ((mrow * 256 + ks * 64 + g * 16) ^ sw));
            acc = MFMA16(af, wkf[ks], acc);
        }
        #pragma unroll
        for (int r = 0; r < 4; ++r) {
            int mk = wv * 64 + qi * 16 + g * 4 + r;
            *(unsigned short*)(smem + 131072 + mk * 32 + 2 * c15) = f2bf(acc[r] + bkv);
        }
    }
    __syncthreads();

    // phase 3: key-tile loop (KV=32, 16 tiles). O[nq 64][c 128] in regs.
    f32x4 o[4][8];
    #pragma unroll
    for (int t = 0; t < 4; ++t)
        #pragma unroll
        for (int ci = 0; ci < 8; ++ci)
            o[t][ci] = zacc;
    float lsum[4] = {0.f, 0.f, 0.f, 0.f};

    for (int kt = 0; kt < 16; ++kt) {
        int mk0 = kt * 32;
        // V tile: wave wv owns output channel rows [16wv, 16wv+16)
        #pragma unroll
        for (int mi = 0; mi < 2; ++mi) {
            f32x4 acc = zacc;
            int mrow = mk0 + mi * 16 + c15;
            int sw = ((mrow >> 2) & 7) << 4;
            #pragma unroll
            for (int ks = 0; ks < 4; ++ks) {
                bf16x8 bf = *(const bf16x8*)(smem + ((mrow * 256 + ks * 64 + g * 16) ^ sw));
                acc = MFMA16(wvf[ks], bf, acc);
            }
            #pragma unroll
            for (int r = 0; r < 4; ++r) {
                int c_out = wv * 16 + g * 4 + r;
                *(unsigned short*)(smem + 147456 + c_out * 80 + 2 * (mi * 16 + c15)) = f2bf(acc[r]);
            }
        }
        __syncthreads();

        // Khat A-frags for this tile (row = mk, k = d)
        bf16x8 ka[2];
        #pragma unroll
        for (int ki = 0; ki < 2; ++ki) {
            bf16x8 v = zfrag;
            if (g < 2) v = *(const bf16x8*)(smem + 131072 + (mk0 + ki * 16 + c15) * 32 + g * 16);
            ka[ki] = v;
        }

        // swapped QK^T -> exp -> redistribute into PV A-frags
        bf16x8 pa[4];
        #pragma unroll
        for (int t = 0; t < 4; ++t) {
            f32x4 s0 = MFMA16(ka[0], qf[t], zacc);   // S^T rows mk0..+15, col nq = 16t+c15
            f32x4 s1 = MFMA16(ka[1], qf[t], zacc);   // rows mk0+16..+31
            float e00 = __expf(s0[0]), e01 = __expf(s0[1]), e02 = __expf(s0[2]), e03 = __expf(s0[3]);
            float e10 = __expf(s1[0]), e11 = __expf(s1[1]), e12 = __expf(s1[2]), e13 = __expf(s1[3]);
            lsum[t] += (e00 + e01) + (e02 + e03) + ((e10 + e11) + (e12 + e13));
            int wA0 = pkbf(e00, e01), wB0 = pkbf(e02, e03);   // ki=0 pairs
            int wA1 = pkbf(e10, e11), wB1 = pkbf(e12, e13);   // ki=1 pairs
            int src1 = ((2 * g) & 3) * 16 + c15;
            int src2 = ((2 * g + 1) & 3) * 16 + c15;
            int sA0a = __shfl(wA0, src1, 64), sA1a = __shfl(wA1, src1, 64);
            int sB0a = __shfl(wB0, src1, 64), sB1a = __shfl(wB1, src1, 64);
            int sA0b = __shfl(wA0, src2, 64), sA1b = __shfl(wA1, src2, 64);
            int sB0b = __shfl(wB0, src2, 64), sB1b = __shfl(wB1, src2, 64);
            bool k1 = (g >= 2);                    // lanes g>=2 need ki=1 source values
            i32x4 uu = { k1 ? sA1a : sA0a, k1 ? sB1a : sB0a,
                         k1 ? sA1b : sA0b, k1 ? sB1b : sB0b };
            pa[t] = __builtin_bit_cast(bf16x8, uu);   // A-frag: row nq=16t+c15, k = mk 8g..8g+7
        }

        // PV: O[nq][c] += P * V  (B-frag col c, k = mk)
        #pragma unroll
        for (int ci = 0; ci < 8; ++ci) {
            bf16x8 vb = *(const bf16x8*)(smem + 147456 + (ci * 16 + c15) * 80 + 16 * g);
            #pragma unroll
            for (int t = 0; t < 4; ++t)
                o[t][ci] = MFMA16(pa[t], vb, o[t][ci]);
        }
        __syncthreads();
    }

    // softmax denominators: reduce across g-groups, store per query
    #pragma unroll
    for (int t = 0; t < 4; ++t) {
        float l = lsum[t];
        l += __shfl_xor(l, 16, 64);
        l += __shfl_xor(l, 32, 64);
        if (g == 0)
            *(float*)(smem + 157696 + (wv * 64 + t * 16 + c15) * 4) = l;
    }

    // O -> LDS (reuse blk^T region), swizzled for conflict-free scalar access
    #pragma unroll
    for (int t = 0; t < 4; ++t)
        #pragma unroll
        for (int ci = 0; ci < 8; ++ci)
            #pragma unroll
            for (int r = 0; r < 4; ++r) {
                int nq = wv * 64 + t * 16 + g * 4 + r;
                int c = ci * 16 + c15;
                *(unsigned short*)(smem + c * 1024 + 2 * (nq ^ ((c & 7) << 3))) = f2bf(o[t][ci][r]);
            }
    __syncthreads();

    // epilogue: out = gamma*(O/l + bv) + x  (x re-read in fp32 for exact residual)
    float gma = gamma[0];
    float invl = 1.0f / *(const float*)(smem + 157696 + tid * 4);
    int vox = ((tid >> 6) << 12) + (((tid >> 3) & 7) << 6) + (tid & 7);
    int go = vbase + vox;
    for (int c = 0; c < 128; ++c) {
        float ov = bf2f(*(const unsigned short*)(smem + c * 1024 + 2 * (tid ^ ((c & 7) << 3))));
        int gidx = c * 262144 + go;
        out[gidx] = gma * (ov * invl + bv[c]) + x[gidx];
    }
}

extern "C" void kernel_launch(void* const* d_in, const int* in_sizes, int n_in,
                              void* d_out, int out_size, void* d_ws, size_t ws_size,
                              hipStream_t stream) {
    const float* x     = (const float*)d_in[0];
    const float* Wq    = (const float*)d_in[1];
    const float* bq    = (const float*)d_in[2];
    const float* Wk    = (const float*)d_in[3];
    const float* bk    = (const float*)d_in[4];
    const float* Wv    = (const float*)d_in[5];
    const float* bv    = (const float*)d_in[6];
    const float* gamma = (const float*)d_in[7];
    float* out = (float*)d_out;
    (void)in_sizes; (void)n_in; (void)out_size; (void)d_ws; (void)ws_size;
    battn_kernel<<<dim3(448), dim3(512), 0, stream>>>(x, Wq, bq, Wk, bk, Wv, bv, gamma, out);
}